// Round 8
// baseline (311.033 us; speedup 1.0000x reference)
//
#include <hip/hip_runtime.h>

// Problem constants (match reference)
constexpr int   T_STEPS = 64;
constexpr int   NN      = 2048;
constexpr float DT_TAU  = 0.1f;    // DT * TAU_MEM_INV
constexpr float V_TH_C  = 1.0f;
constexpr float TRC     = 0.05f;   // DT * TAU_PRE_INV == DT * TAU_POST_INV
constexpr float ETA     = 1e-3f;   // ETA_PLUS == ETA_MINUS

// 256 blocks x 512 threads (cooperative, 1 block/CU). Block b owns neurons
// [8b, 8b+8); wave w owns neuron 8b+w (w-row in 32 VGPR/lane; v/tpo/isyn
// replicated across its 64 lanes). z/tp replicated per block in LDS,
// DOUBLE-BUFFERED by step parity, rebuilt each step from published words.
//
// HARD-WON EXCHANGE RULES (r1/r2/r4/r5/r6):
//  - Each block's published word on a PRIVATE 128B line (r2: 244->203).
//  - EXACTLY 256 pollers/block, one word each (r5: 512/line -> 181->217;
//    agent-scope atomic loads issue PER LANE, no same-address merge).
//  - Publish by the 8TH ARRIVER via LDS atomic (r4: 203->181).
//  - LDS bank conflicts of ~2-8M are FULLY HIDDEN under the exchange wait
//    (r4 2.58M vs r6 8.26M: identical 181us) -> put unavoidable conflicts on
//    the poller WRITE side (hidden), keep phase-C reads stride-1 (critical).
//
// Step k (ONE barrier; buf = k&1):
//  a. LIF from register isyn -> z; v,tpo in regs; pollers issue a PREFETCH
//     load of their word (stale-tolerant); lane0: ds-atomic arrive on
//     word_s[par] (add (1<<24)|(z<<wv)); 8th arriver resets word_s and
//     publishes ONE tagged u64 ((k+1)<<32|bits); then raster store.
//  b. pollers tid<256 spin on word tid (tag k+1, s_sleep backoff), unpack 8
//     neurons into z_db[par] slots {2tid,2tid+1} (write-side conflicts,
//     hidden); tp for those 8 neurons persistent in poller regs, mirrored to
//     tp_db[par].
//     __syncthreads  (RAW: b-writes visible before C-reads)
//  c. fused STDP w-update + matvec reading z_db[par]/tp_db[par] stride-1.
//     WAVE-UNIFORM zi fast path: if own neuron didn't spike, dw has no
//     +ETA*tp term -> nw = zj ? clip(w-etp) : w with etp = ETA*tpoi
//     (bit-exact: 0*tj=+0, w+(+0)=w, w+(0-etp)=w-etp, clip(w)=w for
//     w in [0,1] which is invariant) and the tj LDS read is SKIPPED.
//     zi=1 branch keeps the original expression verbatim.
//     Butterfly -> isyn in regs; prefetch next x. NO second barrier:
//     double-buffering makes b(k+1)/C(k) WAR-free (thread's own C(k)
//     precedes its b(k+1); any b(k+2) is after barrier(k+1) > all C(k)).
//
// Cross-block safety: message==data (bits ride in the tagged word, single 8B
// atomic); tags 1..64 never match 0x00/0xAA poison; parity double-buffer +
// publish gating chain: P overwrites its slot (tag k+3) only after P's
// b(k+1) consumed ALL tags k+2 from every block, each of which required that
// block's b(k) to have consumed tag k+1 (through its barrier(k)) -> a poller
// spinning '!=' for tag k+1 can never be skipped. word_s[par] reset at a(k)
// is ordered before arrivals at a(k+2) by barriers k and k+1. No ws
// initialization needed.
constexpr int BLOCKS  = 256;
constexpr int THREADS = 512;
constexpr int ROWS_PER_BLOCK = NN / BLOCKS;   // 8 == waves per block
constexpr int CHUNKS = NN / 256;              // 8 float4 chunks per lane

__global__ __launch_bounds__(THREADS)
void snn_msg_kernel(const float* __restrict__ x,       // [T, N]
                    const float* __restrict__ w_in,    // [N, N] pristine (never written)
                    const float* __restrict__ tpre0,   // [N]
                    const float* __restrict__ tpost0,  // [N]
                    unsigned long long* __restrict__ zpub, // [2][BLOCKS*stride]
                    int stride,                        // u64 units between words
                    float*       __restrict__ out)     // [T, N] spikes
{
    const int bid  = blockIdx.x;
    const int tid  = threadIdx.x;
    const int wv   = tid >> 6;
    const int lane = tid & 63;
    const int row  = bid * ROWS_PER_BLOCK + wv;   // this wave's neuron / w row

    __shared__ __align__(16) float z_db[2][NN];   // double-buffered spike vector
    __shared__ __align__(16) float tp_db[2][NN];  // double-buffered pre-trace
    __shared__ __align__(16) float x_s[T_STEPS * ROWS_PER_BLOCK]; // owned inputs
    __shared__ unsigned word_s[2];                // [parity] count<<24 | bits

    // Poller tid (<256) owns neurons [8tid, 8tid+8): tp persistent in regs.
    float4 tpA = make_float4(0.f, 0.f, 0.f, 0.f);
    float4 tpB = tpA;
    if (tid < BLOCKS) {
        tpA = ((const float4*)tpre0)[2 * tid];
        tpB = ((const float4*)tpre0)[2 * tid + 1];
    }

    // Stage ALL owned inputs x[t][8b..8b+8) into LDS once.
    x_s[tid] = x[(size_t)(tid >> 3) * NN + bid * ROWS_PER_BLOCK + (tid & 7)];

    if (tid < 2) word_s[tid] = 0u;

    // Own-neuron state, replicated across all 64 lanes.
    float v_own   = 0.0f;
    float tpo_own = tpost0[row];          // broadcast load

    // This wave's w row: chunk c holds w[row][(c*64+lane)*4 ..+3].
    const float4* wrow4 = (const float4*)(w_in + (size_t)row * NN);
    float4 wreg[CHUNKS];
    #pragma unroll
    for (int c = 0; c < CHUNKS; ++c) wreg[c] = wrow4[c * 64 + lane];

    float isyn = 0.0f;                    // w @ z carry, lives in registers
    float xk   = 0.0f;                    // prefetched input current
    __syncthreads();
    xk = x_s[wv];                         // x[0][row] (post-barrier: x_s ready)

    for (int k = 0; k < T_STEPS; ++k) {
        const int par = k & 1;

        // ---- a: LIF (all lanes redundantly); prefetch poll; arrive/publish ----
        float v = v_own + DT_TAU * ((0.0f - v_own) + isyn + xk);
        float z = (v - V_TH_C > 0.0f) ? 1.0f : 0.0f;
        v_own   = v * (1.0f - z);
        tpo_own = tpo_own + TRC * (-tpo_own + z);   // post-trace (post-update
                                                    // value feeds C, as in ref)
        const unsigned long long* pollp = nullptr;
        unsigned long long pref = 0;
        if (tid < BLOCKS && k + 1 < T_STEPS) {
            pollp = &zpub[(size_t)(par * BLOCKS + tid) * stride];
            // stale-tolerant prefetch: overlaps load latency with phase a
            pref = __hip_atomic_load(pollp, __ATOMIC_RELAXED,
                                     __HIP_MEMORY_SCOPE_AGENT);
        }
        if (lane == 0) {
            if (k + 1 < T_STEPS) {
                unsigned add = 0x01000000u | (z > 0.0f ? (1u << wv) : 0u);
                unsigned old = __hip_atomic_fetch_add(&word_s[par], add,
                                   __ATOMIC_RELAXED, __HIP_MEMORY_SCOPE_WORKGROUP);
                if ((old >> 24) == 7u) {            // 8th arriver publishes
                    unsigned bits = (old + add) & 0xFFu;
                    __hip_atomic_store(&word_s[par], 0u,
                                       __ATOMIC_RELAXED, __HIP_MEMORY_SCOPE_WORKGROUP);
                    unsigned long long wrd =
                        ((unsigned long long)(unsigned)(k + 1) << 32) | bits;
                    __hip_atomic_store(&zpub[(size_t)(par * BLOCKS + bid) * stride],
                                       wrd, __ATOMIC_RELAXED,
                                       __HIP_MEMORY_SCOPE_AGENT);
                }
            }
            out[(size_t)k * NN + row] = z;          // raster AFTER publish
        }
        if (k == T_STEPS - 1) break;   // raster[63] written; no exchange needed

        // ---- b: 256 pollers, one word each; unpack to z_db/tp_db[par] ----
        if (tid < BLOCKS) {
            unsigned long long pv = pref;
            while ((unsigned)(pv >> 32) != (unsigned)(k + 1)) {
                __builtin_amdgcn_s_sleep(1);   // ~64cy backoff
                pv = __hip_atomic_load(pollp, __ATOMIC_RELAXED,
                                       __HIP_MEMORY_SCOPE_AGENT);
            }
            const unsigned bits = (unsigned)pv;   // z of neurons 8*tid..8*tid+7
            float4 zA, zB;
            zA.x = (bits & 0x01u) ? 1.0f : 0.0f;
            zA.y = (bits & 0x02u) ? 1.0f : 0.0f;
            zA.z = (bits & 0x04u) ? 1.0f : 0.0f;
            zA.w = (bits & 0x08u) ? 1.0f : 0.0f;
            zB.x = (bits & 0x10u) ? 1.0f : 0.0f;
            zB.y = (bits & 0x20u) ? 1.0f : 0.0f;
            zB.z = (bits & 0x40u) ? 1.0f : 0.0f;
            zB.w = (bits & 0x80u) ? 1.0f : 0.0f;
            // identical per-element expression as always -> bit-exact
            tpA.x = tpA.x + TRC * (-tpA.x + zA.x);
            tpA.y = tpA.y + TRC * (-tpA.y + zA.y);
            tpA.z = tpA.z + TRC * (-tpA.z + zA.z);
            tpA.w = tpA.w + TRC * (-tpA.w + zA.w);
            tpB.x = tpB.x + TRC * (-tpB.x + zB.x);
            tpB.y = tpB.y + TRC * (-tpB.y + zB.y);
            tpB.z = tpB.z + TRC * (-tpB.z + zB.z);
            tpB.w = tpB.w + TRC * (-tpB.w + zB.w);
            // natural layout (phase-C stride-1 reads); write-side conflicts
            // are hidden under the exchange wait (r4 vs r6 evidence)
            ((float4*)z_db[par])[2 * tid]      = zA;
            ((float4*)z_db[par])[2 * tid + 1]  = zB;
            ((float4*)tp_db[par])[2 * tid]     = tpA;
            ((float4*)tp_db[par])[2 * tid + 1] = tpB;
        }
        __syncthreads();               // RAW: b-writes -> C-reads (the ONLY
                                       // per-step barrier; WAR removed by
                                       // the z/tp double-buffer)

        // ---- c: fused STDP w-update + matvec (bit-exact order: c=0..7, xyzw) ----
        const float zi_own = z;        // own neuron's spike (wave-uniform)
        const float tpoi   = tpo_own;  // own neuron's post-trace
        xk = x_s[(k + 1) * ROWS_PER_BLOCK + wv];   // prefetch next input
        float acc = 0.0f;
        const float4* z4s  = (const float4*)z_db[par];
        const float4* tp4s = (const float4*)tp_db[par];
        if (zi_own != 0.0f) {
            // own neuron spiked: ORIGINAL expression verbatim (zi_own = 1.0)
            #pragma unroll
            for (int c = 0; c < CHUNKS; ++c) {
                float4 zj = z4s[c * 64 + lane];
                float4 tj = tp4s[c * 64 + lane];
                float nw;
                nw = wreg[c].x + (ETA * (zi_own * tj.x) - ETA * (tpoi * zj.x));
                nw = fminf(fmaxf(nw, 0.0f), 1.0f); wreg[c].x = nw; acc += nw * zj.x;
                nw = wreg[c].y + (ETA * (zi_own * tj.y) - ETA * (tpoi * zj.y));
                nw = fminf(fmaxf(nw, 0.0f), 1.0f); wreg[c].y = nw; acc += nw * zj.y;
                nw = wreg[c].z + (ETA * (zi_own * tj.z) - ETA * (tpoi * zj.z));
                nw = fminf(fmaxf(nw, 0.0f), 1.0f); wreg[c].z = nw; acc += nw * zj.z;
                nw = wreg[c].w + (ETA * (zi_own * tj.w) - ETA * (tpoi * zj.w));
                nw = fminf(fmaxf(nw, 0.0f), 1.0f); wreg[c].w = nw; acc += nw * zj.w;
            }
        } else {
            // zi = 0 fast path, provably bit-exact vs the original:
            //  ETA*(0*tj) = +0 (tj>=0);  w + (+0 - q) == w - q  (IEEE);
            //  zj=0: q=+0, nw = clip(w) == w  (w in [0,1] invariant);
            //  zj=1: q = ETA*(tpoi*1) == etp (same product), nw = clip(w-etp).
            // tj is NOT read at all (halves phase-C LDS traffic on this path).
            const float etp = ETA * tpoi;
            #pragma unroll
            for (int c = 0; c < CHUNKS; ++c) {
                float4 zj = z4s[c * 64 + lane];
                float nw, nwc;
                nwc = fminf(fmaxf(wreg[c].x - etp, 0.0f), 1.0f);
                nw  = (zj.x != 0.0f) ? nwc : wreg[c].x;
                wreg[c].x = nw; acc += nw * zj.x;
                nwc = fminf(fmaxf(wreg[c].y - etp, 0.0f), 1.0f);
                nw  = (zj.y != 0.0f) ? nwc : wreg[c].y;
                wreg[c].y = nw; acc += nw * zj.y;
                nwc = fminf(fmaxf(wreg[c].z - etp, 0.0f), 1.0f);
                nw  = (zj.z != 0.0f) ? nwc : wreg[c].z;
                wreg[c].z = nw; acc += nw * zj.z;
                nwc = fminf(fmaxf(wreg[c].w - etp, 0.0f), 1.0f);
                nw  = (zj.w != 0.0f) ? nwc : wreg[c].w;
                wreg[c].w = nw; acc += nw * zj.w;
            }
        }
        #pragma unroll
        for (int m = 32; m >= 1; m >>= 1) acc += __shfl_xor(acc, m, 64);
        isyn = acc;                    // i_syn for step k+1, in registers
    }
}

extern "C" void kernel_launch(void* const* d_in, const int* in_sizes, int n_in,
                              void* d_out, int out_size, void* d_ws, size_t ws_size,
                              hipStream_t stream) {
    const float* x     = (const float*)d_in[0];   // [T,N]
    const float* w_in  = (const float*)d_in[1];   // [N,N]
    const float* tpre  = (const float*)d_in[2];   // [N]
    const float* tpost = (const float*)d_in[3];   // [N]
    float*       out   = (float*)d_out;           // [T,N]

    unsigned long long* zpub = (unsigned long long*)d_ws;

    // Pad each published word to its own line if the workspace allows:
    // 128B stride (TCC line) needs 64KB, 64B needs 32KB, else packed (4KB).
    int stride;
    if      (ws_size >= (size_t)2 * BLOCKS * 16 * sizeof(unsigned long long)) stride = 16;
    else if (ws_size >= (size_t)2 * BLOCKS *  8 * sizeof(unsigned long long)) stride = 8;
    else                                                                      stride = 1;

    void* args[] = {(void*)&x, (void*)&w_in, (void*)&tpre, (void*)&tpost,
                    (void*)&zpub, (void*)&stride, (void*)&out};
    hipLaunchCooperativeKernel((void*)snn_msg_kernel,
                               dim3(BLOCKS), dim3(THREADS),
                               args, 0, stream);
}